// Round 1
// baseline (1096.132 us; speedup 1.0000x reference)
//
#include <hip/hip_runtime.h>
#include <math.h>

typedef __attribute__((ext_vector_type(4))) float f32x4;
typedef __attribute__((ext_vector_type(8))) short bf16x8;
typedef __attribute__((ext_vector_type(4))) unsigned short u16x4;

__device__ __forceinline__ unsigned short f2bf(float f) {
  unsigned u = __builtin_bit_cast(unsigned, f);
  u += 0x7fffu + ((u >> 16) & 1u);
  return (unsigned short)(u >> 16);
}
__device__ __forceinline__ float sigmoidf_(float x) { return 1.f / (1.f + __expf(-x)); }

// ---------------------------------------------------------------------------
// Generic bf16-MFMA GEMM: C[M,N] = A[M,K] @ B[N,K]^T (+bias) with epilogues.
// A/B are fp32 in global, converted to bf16 during LDS staging.
// AMODE: 0 = single A; 1 = K-concat (A1 for k<Ksplit, A2 after)
// BMODE: 0 = single B; 1 = K-concat (B1/B2)
// EPI:   0 = C = (acc+bias)*scale
//        1 = C = acc+bias + P0[off] + P1[off]                  (routed)
//        2 = C = (P2+P3+ce + sig(acc+bias)*(P1-ce))/3, ce=P0[row*256+(col&255)]  (final)
// Tile: BM=BN=128, BK=32, 256 threads (4 waves, each 64x64 of 16x16x32 frags).
// Requires M%128==0, N%128==0, K%32==0, Ksplit%32==0.
// ---------------------------------------------------------------------------
template <int AMODE, int BMODE, int EPI>
__global__ __launch_bounds__(256) void gemm_k(
    const float* __restrict__ A1, int lda1, const float* __restrict__ A2, int lda2, int Ksplit,
    const float* __restrict__ B1, int ldb1, const float* __restrict__ B2, int ldb2,
    const float* __restrict__ bias1, const float* __restrict__ bias2,
    float* __restrict__ C, int ldc,
    int M, int N, int K, float scale,
    int aZoff, long bZoff, int cZoff, int biasZoff,
    const float* __restrict__ P0, const float* __restrict__ P1,
    const float* __restrict__ P2, const float* __restrict__ P3) {
  __shared__ unsigned short As[128][32];
  __shared__ unsigned short Bs[128][32];
  const int t = threadIdx.x;
  const int lane = t & 63;
  const int wave = t >> 6;
  const int wr = wave >> 1, wc = wave & 1;
  const int bm = blockIdx.y, bn = blockIdx.x, z = blockIdx.z;

  const float* A1z = A1 + (long)z * aZoff;
  const float* B1z = B1 + (long)z * bZoff;

  f32x4 acc[4][4] = {};
  const int kIters = K >> 5;
  for (int kt = 0; kt < kIters; ++kt) {
    const int k0 = kt << 5;
    const float* Ab;
    int ldA, kA;
    if (AMODE == 1 && k0 >= Ksplit) { Ab = A2; ldA = lda2; kA = k0 - Ksplit; }
    else { Ab = A1z; ldA = lda1; kA = k0; }
    const float* Bb;
    int ldB, kB;
    if (BMODE == 1 && k0 >= Ksplit) { Bb = B2; ldB = ldb2; kB = k0 - Ksplit; }
    else { Bb = B1z; ldB = ldb1; kB = k0; }

    __syncthreads();
#pragma unroll
    for (int i = 0; i < 4; ++i) {
      const int ar = (t >> 3) + 32 * i;
      const int bc = (t & 7) * 4;
      f32x4 av = *(const f32x4*)(Ab + ((long)bm * 128 + ar) * ldA + kA + bc);
      u16x4 ap;
      ap[0] = f2bf(av[0]); ap[1] = f2bf(av[1]); ap[2] = f2bf(av[2]); ap[3] = f2bf(av[3]);
      *(u16x4*)&As[ar][bc] = ap;
      f32x4 bv = *(const f32x4*)(Bb + ((long)bn * 128 + ar) * ldB + kB + bc);
      u16x4 bp;
      bp[0] = f2bf(bv[0]); bp[1] = f2bf(bv[1]); bp[2] = f2bf(bv[2]); bp[3] = f2bf(bv[3]);
      *(u16x4*)&Bs[ar][bc] = bp;
    }
    __syncthreads();

    bf16x8 af[4], bf[4];
#pragma unroll
    for (int mi = 0; mi < 4; ++mi)
      af[mi] = *(const bf16x8*)&As[wr * 64 + mi * 16 + (lane & 15)][(lane >> 4) * 8];
#pragma unroll
    for (int ni = 0; ni < 4; ++ni)
      bf[ni] = *(const bf16x8*)&Bs[wc * 64 + ni * 16 + (lane & 15)][(lane >> 4) * 8];
#pragma unroll
    for (int mi = 0; mi < 4; ++mi)
#pragma unroll
      for (int ni = 0; ni < 4; ++ni)
        acc[mi][ni] = __builtin_amdgcn_mfma_f32_16x16x32_bf16(af[mi], bf[ni], acc[mi][ni], 0, 0, 0);
  }

  float* Cz = C + (long)z * cZoff;
  const int colb = bn * 128 + wc * 64;
  const int rowb = bm * 128 + wr * 64;
#pragma unroll
  for (int mi = 0; mi < 4; ++mi) {
#pragma unroll
    for (int ni = 0; ni < 4; ++ni) {
      f32x4 v = acc[mi][ni];
      const int col = colb + ni * 16 + (lane & 15);
      const int row0 = rowb + mi * 16 + ((lane >> 4) << 2);
      float bsum = 0.f;
      if (bias1) bsum += bias1[(long)z * biasZoff + col];
      if (bias2) bsum += bias2[(long)z * biasZoff + col];
#pragma unroll
      for (int q = 0; q < 4; ++q) {
        const long row = row0 + q;
        const long off = row * ldc + col;
        const float val = v[q] + bsum;
        if (EPI == 0) {
          Cz[off] = val * scale;
        } else if (EPI == 1) {
          Cz[off] = val + P0[off] + P1[off];
        } else {
          const float g = sigmoidf_(val);
          const float ce = P0[row * 256 + (col & 255)];
          const float ex = P1[off];
          Cz[off] = (P2[off] + P3[off] + ce + g * (ex - ce)) * (1.f / 3.f);
        }
      }
    }
  }
}

// 64x64 LDS-tiled transpose: out[n][d] = in[d][n], n = 1024
__global__ __launch_bounds__(256) void transpose_k(const float* __restrict__ in,
                                                   float* __restrict__ out, int n) {
  __shared__ float tile[64][65];
  const int tr = blockIdx.y, tc = blockIdx.x, t = threadIdx.x;
#pragma unroll
  for (int it = 0; it < 16; ++it) {
    int idx = t + 256 * it;
    int r = idx >> 6, c = idx & 63;
    tile[r][c] = in[(long)(tr * 64 + r) * n + tc * 64 + c];
  }
  __syncthreads();
#pragma unroll
  for (int it = 0; it < 16; ++it) {
    int idx = t + 256 * it;
    int rr = idx >> 6, cc = idx & 63;
    out[(long)(tc * 64 + rr) * n + tr * 64 + cc] = tile[cc][rr];
  }
}

// LSTM elementwise: gates [B,4096] order i,f,g,o
__global__ __launch_bounds__(256) void lstm_k(const float* __restrict__ gates,
                                              const float* __restrict__ c_in,
                                              float* __restrict__ c_out,
                                              float* __restrict__ h_ws,
                                              float* __restrict__ h_out) {
  const long i4 = (long)blockIdx.x * 256 + threadIdx.x;  // float4 index over B*H/4
  const long b = i4 >> 8;
  const int j = (int)(i4 & 255) * 4;
  const float* gb = gates + b * 4096;
  f32x4 gi = *(const f32x4*)(gb + j);
  f32x4 gf = *(const f32x4*)(gb + 1024 + j);
  f32x4 gg = *(const f32x4*)(gb + 2048 + j);
  f32x4 go = *(const f32x4*)(gb + 3072 + j);
  f32x4 cv = *(const f32x4*)(c_in + i4 * 4);
  f32x4 cn, hv;
#pragma unroll
  for (int q = 0; q < 4; ++q) {
    float cc = sigmoidf_(gf[q]) * cv[q] + sigmoidf_(gi[q]) * tanhf(gg[q]);
    cn[q] = cc;
    hv[q] = sigmoidf_(go[q]) * tanhf(cc);
  }
  *(f32x4*)(c_out + i4 * 4) = cn;
  *(f32x4*)(h_ws + i4 * 4) = hv;
  *(f32x4*)(h_out + i4 * 4) = hv;
}

// router: rw[b,:] = softmax(h_lstm[b]@Wrout^T + brout), one wave per b
__global__ __launch_bounds__(64) void router_k(const float* __restrict__ hl,
                                               const float* __restrict__ Wr,
                                               const float* __restrict__ br,
                                               float* __restrict__ rw) {
  const int b = blockIdx.x, lane = threadIdx.x;
  float a0 = 0.f, a1 = 0.f;
  for (int k = lane; k < 1024; k += 64) {
    float h = hl[(long)b * 1024 + k];
    a0 += h * Wr[k];
    a1 += h * Wr[1024 + k];
  }
#pragma unroll
  for (int m = 32; m >= 1; m >>= 1) {
    a0 += __shfl_xor(a0, m);
    a1 += __shfl_xor(a1, m);
  }
  if (lane == 0) {
    float z0 = a0 + br[0], z1 = a1 + br[1];
    float mx = fmaxf(z0, z1);
    float e0 = __expf(z0 - mx), e1 = __expf(z1 - mx);
    float s = e0 + e1;
    rw[2 * b] = e0 / s;
    rw[2 * b + 1] = e1 / s;
  }
}

__global__ __launch_bounds__(256) void combine_k(const float* __restrict__ so,
                                                 const float* __restrict__ eo,
                                                 const float* __restrict__ rw,
                                                 float* __restrict__ ra) {
  const long i4 = (long)blockIdx.x * 256 + threadIdx.x;
  const long b = i4 >> 8;
  const float w0 = rw[2 * b], w1 = rw[2 * b + 1];
  f32x4 s = *(const f32x4*)(so + i4 * 4);
  f32x4 e = *(const f32x4*)(eo + i4 * 4);
  f32x4 r;
#pragma unroll
  for (int q = 0; q < 4; ++q) r[q] = w0 * s[q] + w1 * e[q];
  *(f32x4*)(ra + i4 * 4) = r;
}

// ---------------------------------------------------------------------------
// Fused attention core (Lq=1): per block b:
//   scores[h,l] = memK_new[l,b,:] . qt[b,h,:]   (fp32, K streamed via LDS)
//   p = softmax_l ; mix[b,h,:] = sum_l p * memV_new[l,b,:]
//   SELF also emits ts[b,:] = mean_l memK_new[l,b,:]
// memX_new row l: SELF ? (l<31 ? memX[l+1] : h_lstm) : extX[l]
// ---------------------------------------------------------------------------
template <bool SELF>
__global__ __launch_bounds__(256) void attn_k(const float* __restrict__ Ksrc,
                                              const float* __restrict__ Vsrc,
                                              const float* __restrict__ hl,
                                              const float* __restrict__ qt,
                                              float* __restrict__ mix,
                                              float* __restrict__ ts) {
  const int NB = 2048, H = 1024;
  __shared__ float tile[32][132];
  __shared__ float p_s[8][32];
  const int b = blockIdx.x, t = threadIdx.x;
  const int head = t >> 5, l = t & 31;
  const float* qrow = qt + (long)b * 8192 + (long)head * 1024;
  float sc = 0.f;

  for (int ch = 0; ch < 8; ++ch) {
    __syncthreads();
#pragma unroll
    for (int it = 0; it < 4; ++it) {
      int f = t + 256 * it;
      int r = f >> 5, c4 = f & 31;
      const float* src;
      if (SELF) src = (r < 31) ? (Ksrc + ((long)(r + 1) * NB + b) * H) : (hl + (long)b * H);
      else      src = Ksrc + ((long)r * NB + b) * H;
      *(f32x4*)&tile[r][c4 * 4] = *(const f32x4*)(src + ch * 128 + c4 * 4);
    }
    __syncthreads();
    if (SELF && t < 128) {
      float s = 0.f;
#pragma unroll
      for (int lr = 0; lr < 32; ++lr) s += tile[lr][t];
      ts[(long)b * H + ch * 128 + t] = s * (1.f / 32.f);
    }
#pragma unroll 8
    for (int c = 0; c < 32; ++c) {
      f32x4 kv = *(const f32x4*)&tile[l][c * 4];
      f32x4 qv = *(const f32x4*)(qrow + ch * 128 + c * 4);
      sc += kv[0] * qv[0] + kv[1] * qv[1] + kv[2] * qv[2] + kv[3] * qv[3];
    }
  }

  float mx = sc;
#pragma unroll
  for (int m = 16; m >= 1; m >>= 1) mx = fmaxf(mx, __shfl_xor(mx, m, 32));
  float p = __expf(sc - mx);
  float sum = p;
#pragma unroll
  for (int m = 16; m >= 1; m >>= 1) sum += __shfl_xor(sum, m, 32);
  p /= sum;
  p_s[head][l] = p;

  for (int ch = 0; ch < 8; ++ch) {
    __syncthreads();
#pragma unroll
    for (int it = 0; it < 4; ++it) {
      int f = t + 256 * it;
      int r = f >> 5, c4 = f & 31;
      const float* src;
      if (SELF) src = (r < 31) ? (Vsrc + ((long)(r + 1) * NB + b) * H) : (hl + (long)b * H);
      else      src = Vsrc + ((long)r * NB + b) * H;
      *(f32x4*)&tile[r][c4 * 4] = *(const f32x4*)(src + ch * 128 + c4 * 4);
    }
    __syncthreads();
    float a0 = 0.f, a1 = 0.f, a2 = 0.f, a3 = 0.f;
#pragma unroll
    for (int lr = 0; lr < 32; ++lr) {
      float pw = p_s[head][lr];
      a0 += pw * tile[lr][l];
      a1 += pw * tile[lr][l + 32];
      a2 += pw * tile[lr][l + 64];
      a3 += pw * tile[lr][l + 96];
    }
    long o = (long)b * 8192 + (long)head * 1024 + ch * 128 + l;
    mix[o] = a0; mix[o + 32] = a1; mix[o + 64] = a2; mix[o + 96] = a3;
  }
}

extern "C" void kernel_launch(void* const* d_in, const int* in_sizes, int n_in,
                              void* d_out, int out_size, void* d_ws, size_t ws_size,
                              hipStream_t stream) {
  const float* x    = (const float*)d_in[0];
  const float* h    = (const float*)d_in[1];
  const float* c    = (const float*)d_in[2];
  const float* memK = (const float*)d_in[3];
  const float* memV = (const float*)d_in[4];
  const float* extK = (const float*)d_in[5];
  const float* extV = (const float*)d_in[6];
  const float* W_ih = (const float*)d_in[7];
  const float* W_hh = (const float*)d_in[8];
  const float* b_ih = (const float*)d_in[9];
  const float* b_hh = (const float*)d_in[10];
  const float* sWq = (const float*)d_in[11];
  const float* sbq = (const float*)d_in[12];
  const float* sWk = (const float*)d_in[13];
  // sbk (14) cancels in softmax
  const float* sWv = (const float*)d_in[15];
  const float* sbv = (const float*)d_in[16];
  const float* sWo = (const float*)d_in[17];
  const float* sbo = (const float*)d_in[18];
  const float* cWq = (const float*)d_in[19];
  const float* cbq = (const float*)d_in[20];
  const float* cWk = (const float*)d_in[21];
  // cbk (22) cancels
  const float* cWv = (const float*)d_in[23];
  const float* cbv = (const float*)d_in[24];
  const float* cWo = (const float*)d_in[25];
  const float* cbo = (const float*)d_in[26];
  const float* Wres = (const float*)d_in[27];
  const float* bres = (const float*)d_in[28];
  const float* Wrout = (const float*)d_in[29];
  const float* brout = (const float*)d_in[30];
  const float* Wcomp = (const float*)d_in[31];
  const float* bcomp = (const float*)d_in[32];
  const float* Wexp = (const float*)d_in[33];
  const float* bexp = (const float*)d_in[34];
  const float* Wgate = (const float*)d_in[35];
  const float* bgate = (const float*)d_in[36];
  (void)in_sizes; (void)n_in; (void)out_size; (void)ws_size;

  float* out = (float*)d_out;
  float* w = (float*)d_ws;
  const long M1 = 1024 * 1024;
  float* gates   = w;            // 8M
  float* hl      = w + 8 * M1;   // 2M
  float* qsS     = w + 10 * M1;  // 2M
  float* qsE     = w + 12 * M1;  // 2M
  float* wkTs    = w + 14 * M1;  // 1M
  float* wkTc    = w + 15 * M1;  // 1M
  float* qtS     = w + 16 * M1;  // 16M
  float* qtE     = w + 32 * M1;  // 16M
  float* mixS    = w + 48 * M1;  // 16M
  float* mixE    = w + 64 * M1;  // 16M
  float* ts      = w + 80 * M1;  // 2M
  float* attnS   = w + 82 * M1;  // 2M
  float* attnE   = w + 84 * M1;  // 2M
  float* selfO   = w + 86 * M1;  // 2M
  float* extO    = w + 88 * M1;  // 2M
  float* rw      = w + 90 * M1;  // 4K
  float* rattn   = w + 91 * M1;  // 2M
  float* routed  = w + 93 * M1;  // 2M
  float* comp    = w + 95 * M1;  // 0.5M
  float* expd    = w + 96 * M1;  // 2M

  float* hFinal_out = out;
  float* hl_out     = out + 2 * M1;
  float* cn_out     = out + 4 * M1;

  const float scaleq = 0.08838834764831845f;  // 1/sqrt(128)
  dim3 blk(256);

  // Wk transposes (fp32): wkT[k][e] = Wk[e][k]
  transpose_k<<<dim3(16, 16), blk, 0, stream>>>(sWk, wkTs, 1024);
  transpose_k<<<dim3(16, 16), blk, 0, stream>>>(cWk, wkTc, 1024);

  // gates = x@W_ih^T + h@W_hh^T + b_ih + b_hh
  gemm_k<1, 1, 0><<<dim3(32, 16, 1), blk, 0, stream>>>(
      x, 1024, h, 1024, 1024, W_ih, 1024, W_hh, 1024, b_ih, b_hh,
      gates, 4096, 2048, 4096, 2048, 1.f, 0, 0, 0, 0, nullptr, nullptr, nullptr, nullptr);

  lstm_k<<<2048, blk, 0, stream>>>(gates, c, cn_out, hl, hl_out);

  // scaled q projections
  gemm_k<0, 0, 0><<<dim3(8, 16, 1), blk, 0, stream>>>(
      hl, 1024, nullptr, 0, 0, sWq, 1024, nullptr, 0, sbq, nullptr,
      qsS, 1024, 2048, 1024, 1024, scaleq, 0, 0, 0, 0, nullptr, nullptr, nullptr, nullptr);
  gemm_k<0, 0, 0><<<dim3(8, 16, 1), blk, 0, stream>>>(
      hl, 1024, nullptr, 0, 0, cWq, 1024, nullptr, 0, cbq, nullptr,
      qsE, 1024, 2048, 1024, 1024, scaleq, 0, 0, 0, 0, nullptr, nullptr, nullptr, nullptr);

  // qt[b,h,k] = sum_d qs[b,h*128+d] * Wk[h*128+d,k]  (B = wkT, per-head z)
  gemm_k<0, 0, 0><<<dim3(8, 16, 8), blk, 0, stream>>>(
      qsS, 1024, nullptr, 0, 0, wkTs, 1024, nullptr, 0, nullptr, nullptr,
      qtS, 8192, 2048, 1024, 128, 1.f, 128, 128, 1024, 0, nullptr, nullptr, nullptr, nullptr);
  gemm_k<0, 0, 0><<<dim3(8, 16, 8), blk, 0, stream>>>(
      qsE, 1024, nullptr, 0, 0, wkTc, 1024, nullptr, 0, nullptr, nullptr,
      qtE, 8192, 2048, 1024, 128, 1.f, 128, 128, 1024, 0, nullptr, nullptr, nullptr, nullptr);

  // fused scores+softmax+V-mix (+temporal summary for self)
  attn_k<true><<<2048, blk, 0, stream>>>(memK, memV, hl, qtS, mixS, ts);
  attn_k<false><<<2048, blk, 0, stream>>>(extK, extV, hl, qtE, mixE, nullptr);

  // attn head outputs: attn[b, h*128+d] = mix[b,h,:] @ Wv[h*128+d,:] + bv
  gemm_k<0, 0, 0><<<dim3(1, 16, 8), blk, 0, stream>>>(
      mixS, 8192, nullptr, 0, 0, sWv, 1024, nullptr, 0, sbv, nullptr,
      attnS, 1024, 2048, 128, 1024, 1.f, 1024, 128 * 1024, 128, 128, nullptr, nullptr, nullptr, nullptr);
  gemm_k<0, 0, 0><<<dim3(1, 16, 8), blk, 0, stream>>>(
      mixE, 8192, nullptr, 0, 0, cWv, 1024, nullptr, 0, cbv, nullptr,
      attnE, 1024, 2048, 128, 1024, 1.f, 1024, 128 * 1024, 128, 128, nullptr, nullptr, nullptr, nullptr);

  // output projections
  gemm_k<0, 0, 0><<<dim3(8, 16, 1), blk, 0, stream>>>(
      attnS, 1024, nullptr, 0, 0, sWo, 1024, nullptr, 0, sbo, nullptr,
      selfO, 1024, 2048, 1024, 1024, 1.f, 0, 0, 0, 0, nullptr, nullptr, nullptr, nullptr);
  gemm_k<0, 0, 0><<<dim3(8, 16, 1), blk, 0, stream>>>(
      attnE, 1024, nullptr, 0, 0, cWo, 1024, nullptr, 0, cbo, nullptr,
      extO, 1024, 2048, 1024, 1024, 1.f, 0, 0, 0, 0, nullptr, nullptr, nullptr, nullptr);

  router_k<<<2048, dim3(64), 0, stream>>>(hl, Wrout, brout, rw);
  combine_k<<<2048, blk, 0, stream>>>(selfO, extO, rw, rattn);

  // routed = h_lstm + routed_attn + routed_attn@Wres^T + bres
  gemm_k<0, 0, 1><<<dim3(8, 16, 1), blk, 0, stream>>>(
      rattn, 1024, nullptr, 0, 0, Wres, 1024, nullptr, 0, bres, nullptr,
      routed, 1024, 2048, 1024, 1024, 1.f, 0, 0, 0, 0, hl, rattn, nullptr, nullptr);

  // compressed / expanded
  gemm_k<0, 0, 0><<<dim3(2, 16, 1), blk, 0, stream>>>(
      ts, 1024, nullptr, 0, 0, Wcomp, 1024, nullptr, 0, bcomp, nullptr,
      comp, 256, 2048, 256, 1024, 1.f, 0, 0, 0, 0, nullptr, nullptr, nullptr, nullptr);
  gemm_k<0, 0, 0><<<dim3(8, 16, 1), blk, 0, stream>>>(
      comp, 256, nullptr, 0, 0, Wexp, 256, nullptr, 0, bexp, nullptr,
      expd, 1024, 2048, 1024, 256, 1.f, 0, 0, 0, 0, nullptr, nullptr, nullptr, nullptr);

  // gate GEMM + fused final: hFinal = (h_lstm + routed + ce + sig(gate)*(exp-ce))/3
  gemm_k<1, 0, 2><<<dim3(8, 16, 1), blk, 0, stream>>>(
      x, 1024, routed, 1024, 1024, Wgate, 2048, nullptr, 0, bgate, nullptr,
      hFinal_out, 1024, 2048, 1024, 2048, 1.f, 0, 0, 0, 0, comp, expd, hl, routed);
}

// Round 2
// 857.401 us; speedup vs baseline: 1.2784x; 1.2784x over previous
//
#include <hip/hip_runtime.h>
#include <math.h>

typedef __attribute__((ext_vector_type(4))) float f32x4;
typedef __attribute__((ext_vector_type(8))) short bf16x8;
typedef __attribute__((ext_vector_type(4))) unsigned short u16x4;

__device__ __forceinline__ unsigned short f2bf(float f) {
  unsigned u = __builtin_bit_cast(unsigned, f);
  u += 0x7fffu + ((u >> 16) & 1u);
  return (unsigned short)(u >> 16);
}
__device__ __forceinline__ float sigmoidf_(float x) { return 1.f / (1.f + __expf(-x)); }

// ---------------------------------------------------------------------------
// bf16-MFMA GEMM, 128x128 tile, BK=32, 4 waves, double-buffered LDS with
// 1-deep register prefetch. C[M,N] = A[M,K] @ B[N,K]^T (+bias), epilogues.
// ACAT/BCAT: K-concat (A1 for k<Ksplit, A2 after). z-split: blocks with
// z >= zs use the "b" pointer set (A1b/B1b/bias1b/Cb) with zz = z - zs.
// EPI: 0 = (acc+bias)*scale ; 1 = acc+bias+P0+P1 ;
//      2 = (P2+P3+ce+sig(acc+bias)*(P1-ce))/3, ce=P0[row*256+(col&255)]
// ---------------------------------------------------------------------------
template <int ACAT, int BCAT, int EPI>
__global__ __launch_bounds__(256) void gemm_k(
    const float* __restrict__ A1, const float* __restrict__ A1b, int lda1, long aZ,
    const float* __restrict__ A2, int lda2, int Ksplit,
    const float* __restrict__ B1, const float* __restrict__ B1b, int ldb1, long bZ,
    const float* __restrict__ B2, int ldb2,
    const float* __restrict__ bias1, const float* __restrict__ bias1b, long biasZ,
    const float* __restrict__ bias2,
    float* __restrict__ C, float* __restrict__ Cb, int ldc, long cZ,
    int K, int zs, float scale,
    const float* __restrict__ P0, const float* __restrict__ P1,
    const float* __restrict__ P2, const float* __restrict__ P3) {
  __shared__ unsigned short As[2][128][32];
  __shared__ unsigned short Bs[2][128][32];
  const int t = threadIdx.x;
  const int lane = t & 63;
  const int wave = t >> 6;
  const int wr = wave >> 1, wc = wave & 1;
  const int bm = blockIdx.y, bn = blockIdx.x, z = blockIdx.z;

  const bool hi = z >= zs;
  const int zz = hi ? z - zs : z;
  const float* Abase = (hi ? A1b : A1) + (long)zz * aZ;
  const float* Bbase = (hi ? B1b : B1) + (long)zz * bZ;
  const float* biasp = hi ? bias1b : bias1;
  float* Cz = (hi ? Cb : C) + (long)zz * cZ;

  const int ar = t >> 3;          // 0..31 (+32*i)
  const int bc = (t & 7) * 4;     // 0..28

  const int kIters = K >> 5;
  f32x4 Ra[4], Rb[4];

  auto loadT = [&](int kt, f32x4* RA, f32x4* RB) {
    const int k0 = kt << 5;
    const float* Ap; int ldA, kA;
    if (ACAT == 1 && k0 >= Ksplit) { Ap = A2; ldA = lda2; kA = k0 - Ksplit; }
    else { Ap = Abase; ldA = lda1; kA = k0; }
    const float* Bp; int ldB, kB;
    if (BCAT == 1 && k0 >= Ksplit) { Bp = B2; ldB = ldb2; kB = k0 - Ksplit; }
    else { Bp = Bbase; ldB = ldb1; kB = k0; }
#pragma unroll
    for (int i = 0; i < 4; ++i) {
      RA[i] = *(const f32x4*)(Ap + ((long)bm * 128 + ar + 32 * i) * ldA + kA + bc);
      RB[i] = *(const f32x4*)(Bp + ((long)bn * 128 + ar + 32 * i) * ldB + kB + bc);
    }
  };

  loadT(0, Ra, Rb);

  f32x4 acc[4][4] = {};
  int p = 0;
  for (int kt = 0; kt < kIters; ++kt) {
    __syncthreads();  // buf[p] free to overwrite
#pragma unroll
    for (int i = 0; i < 4; ++i) {
      u16x4 ap;
      ap[0] = f2bf(Ra[i][0]); ap[1] = f2bf(Ra[i][1]); ap[2] = f2bf(Ra[i][2]); ap[3] = f2bf(Ra[i][3]);
      *(u16x4*)&As[p][ar + 32 * i][bc] = ap;
      u16x4 bp;
      bp[0] = f2bf(Rb[i][0]); bp[1] = f2bf(Rb[i][1]); bp[2] = f2bf(Rb[i][2]); bp[3] = f2bf(Rb[i][3]);
      *(u16x4*)&Bs[p][ar + 32 * i][bc] = bp;
    }
    if (kt + 1 < kIters) loadT(kt + 1, Ra, Rb);
    __syncthreads();  // buf[p] staged

    bf16x8 af[4], bfr[4];
#pragma unroll
    for (int mi = 0; mi < 4; ++mi)
      af[mi] = *(const bf16x8*)&As[p][wr * 64 + mi * 16 + (lane & 15)][(lane >> 4) * 8];
#pragma unroll
    for (int ni = 0; ni < 4; ++ni)
      bfr[ni] = *(const bf16x8*)&Bs[p][wc * 64 + ni * 16 + (lane & 15)][(lane >> 4) * 8];
#pragma unroll
    for (int mi = 0; mi < 4; ++mi)
#pragma unroll
      for (int ni = 0; ni < 4; ++ni)
        acc[mi][ni] = __builtin_amdgcn_mfma_f32_16x16x32_bf16(af[mi], bfr[ni], acc[mi][ni], 0, 0, 0);
    p ^= 1;
  }

  const int colb = bn * 128 + wc * 64;
  const int rowb = bm * 128 + wr * 64;
#pragma unroll
  for (int mi = 0; mi < 4; ++mi) {
#pragma unroll
    for (int ni = 0; ni < 4; ++ni) {
      f32x4 v = acc[mi][ni];
      const int col = colb + ni * 16 + (lane & 15);
      const int row0 = rowb + mi * 16 + ((lane >> 4) << 2);
      float bsum = 0.f;
      if (biasp) bsum += biasp[zz * biasZ + col];
      if (bias2) bsum += bias2[col];
#pragma unroll
      for (int q = 0; q < 4; ++q) {
        const long row = row0 + q;
        const long off = row * ldc + col;
        const float val = v[q] + bsum;
        if (EPI == 0) {
          Cz[off] = val * scale;
        } else if (EPI == 1) {
          Cz[off] = val + P0[off] + P1[off];
        } else {
          const float g = sigmoidf_(val);
          const float ce = P0[row * 256 + (col & 255)];
          const float ex = P1[off];
          Cz[off] = (P2[off] + P3[off] + ce + g * (ex - ce)) * (1.f / 3.f);
        }
      }
    }
  }
}

// 64x64 LDS-tiled transpose: out[n][d] = in[d][n], n = 1024
__global__ __launch_bounds__(256) void transpose_k(const float* __restrict__ in,
                                                   float* __restrict__ out, int n) {
  __shared__ float tile[64][65];
  const int tr = blockIdx.y, tc = blockIdx.x, t = threadIdx.x;
#pragma unroll
  for (int it = 0; it < 16; ++it) {
    int idx = t + 256 * it;
    int r = idx >> 6, c = idx & 63;
    tile[r][c] = in[(long)(tr * 64 + r) * n + tc * 64 + c];
  }
  __syncthreads();
#pragma unroll
  for (int it = 0; it < 16; ++it) {
    int idx = t + 256 * it;
    int rr = idx >> 6, cc = idx & 63;
    out[(long)(tc * 64 + rr) * n + tr * 64 + cc] = tile[cc][rr];
  }
}

// LSTM elementwise: gates [B,4096] order i,f,g,o
__global__ __launch_bounds__(256) void lstm_k(const float* __restrict__ gates,
                                              const float* __restrict__ c_in,
                                              float* __restrict__ c_out,
                                              float* __restrict__ h_ws,
                                              float* __restrict__ h_out) {
  const long i4 = (long)blockIdx.x * 256 + threadIdx.x;
  const long b = i4 >> 8;
  const int j = (int)(i4 & 255) * 4;
  const float* gb = gates + b * 4096;
  f32x4 gi = *(const f32x4*)(gb + j);
  f32x4 gf = *(const f32x4*)(gb + 1024 + j);
  f32x4 gg = *(const f32x4*)(gb + 2048 + j);
  f32x4 go = *(const f32x4*)(gb + 3072 + j);
  f32x4 cv = *(const f32x4*)(c_in + i4 * 4);
  f32x4 cn, hv;
#pragma unroll
  for (int q = 0; q < 4; ++q) {
    float cc = sigmoidf_(gf[q]) * cv[q] + sigmoidf_(gi[q]) * tanhf(gg[q]);
    cn[q] = cc;
    hv[q] = sigmoidf_(go[q]) * tanhf(cc);
  }
  *(f32x4*)(c_out + i4 * 4) = cn;
  *(f32x4*)(h_ws + i4 * 4) = hv;
  *(f32x4*)(h_out + i4 * 4) = hv;
}

// router: rw[b,:] = softmax(h_lstm[b]@Wrout^T + brout), one wave per b
__global__ __launch_bounds__(64) void router_k(const float* __restrict__ hl,
                                               const float* __restrict__ Wr,
                                               const float* __restrict__ br,
                                               float* __restrict__ rw) {
  const int b = blockIdx.x, lane = threadIdx.x;
  float a0 = 0.f, a1 = 0.f;
  for (int k = lane; k < 1024; k += 64) {
    float h = hl[(long)b * 1024 + k];
    a0 += h * Wr[k];
    a1 += h * Wr[1024 + k];
  }
#pragma unroll
  for (int m = 32; m >= 1; m >>= 1) {
    a0 += __shfl_xor(a0, m);
    a1 += __shfl_xor(a1, m);
  }
  if (lane == 0) {
    float z0 = a0 + br[0], z1 = a1 + br[1];
    float mx = fmaxf(z0, z1);
    float e0 = __expf(z0 - mx), e1 = __expf(z1 - mx);
    float s = e0 + e1;
    rw[2 * b] = e0 / s;
    rw[2 * b + 1] = e1 / s;
  }
}

__global__ __launch_bounds__(256) void combine_k(const float* __restrict__ so,
                                                 const float* __restrict__ eo,
                                                 const float* __restrict__ rw,
                                                 float* __restrict__ ra) {
  const long i4 = (long)blockIdx.x * 256 + threadIdx.x;
  const long b = i4 >> 8;
  const float w0 = rw[2 * b], w1 = rw[2 * b + 1];
  f32x4 s = *(const f32x4*)(so + i4 * 4);
  f32x4 e = *(const f32x4*)(eo + i4 * 4);
  f32x4 r;
#pragma unroll
  for (int q = 0; q < 4; ++q) r[q] = w0 * s[q] + w1 * e[q];
  *(f32x4*)(ra + i4 * 4) = r;
}

// ---------------------------------------------------------------------------
// Fused attention (Lq=1), self+ext merged (blockIdx.y), double-buffered LDS
// with 1-deep register prefetch. Per block (b, y):
//   scores[h,l] = rows[l] . qt[b,h,:]; p = softmax_l; mix = sum_l p*Vrows[l]
//   self (y==0) additionally writes ts[b,:] = mean_l Krows[l]
// rows: self -> memX rows 1..31 then h_lstm; ext -> extX rows 0..31.
// ---------------------------------------------------------------------------
__global__ __launch_bounds__(256) void attn2_k(
    const float* __restrict__ memK, const float* __restrict__ memV,
    const float* __restrict__ extK, const float* __restrict__ extV,
    const float* __restrict__ hl,
    const float* __restrict__ qtS, const float* __restrict__ qtE,
    float* __restrict__ mixS, float* __restrict__ mixE,
    float* __restrict__ ts) {
  const int NB = 2048, H = 1024;
  __shared__ float tile[2][32][132];
  __shared__ float p_s[8][32];
  const int b = blockIdx.x;
  const bool self = blockIdx.y == 0;
  const int t = threadIdx.x;
  const int head = t >> 5, l = t & 31;
  const float* qrow = (self ? qtS : qtE) + (long)b * 8192 + (long)head * 1024;
  float* mix = (self ? mixS : mixE) + (long)b * 8192;

  const float* baseK[4];
  const float* baseV[4];
  int rr[4], cc4[4];
#pragma unroll
  for (int it = 0; it < 4; ++it) {
    int f = t + 256 * it;
    int r = f >> 5, c4 = f & 31;
    rr[it] = r; cc4[it] = c4;
    if (self) {
      baseK[it] = (r < 31) ? (memK + ((long)(r + 1) * NB + b) * H) : (hl + (long)b * H);
      baseV[it] = (r < 31) ? (memV + ((long)(r + 1) * NB + b) * H) : (hl + (long)b * H);
    } else {
      baseK[it] = extK + ((long)r * NB + b) * H;
      baseV[it] = extV + ((long)r * NB + b) * H;
    }
  }

  f32x4 R[4];
#pragma unroll
  for (int it = 0; it < 4; ++it) R[it] = *(const f32x4*)(baseK[it] + cc4[it] * 4);

  float sc = 0.f;
  int p = 0;
  for (int ch = 0; ch < 8; ++ch) {
    __syncthreads();  // buf[p] free
#pragma unroll
    for (int it = 0; it < 4; ++it) *(f32x4*)&tile[p][rr[it]][cc4[it] * 4] = R[it];
    if (ch < 7) {
#pragma unroll
      for (int it = 0; it < 4; ++it)
        R[it] = *(const f32x4*)(baseK[it] + (ch + 1) * 128 + cc4[it] * 4);
    } else {
#pragma unroll
      for (int it = 0; it < 4; ++it)  // prefetch V chunk 0 under softmax
        R[it] = *(const f32x4*)(baseV[it] + cc4[it] * 4);
    }
    __syncthreads();  // buf[p] staged
    if (self && t < 128) {
      float s = 0.f;
#pragma unroll
      for (int lr = 0; lr < 32; ++lr) s += tile[p][lr][t];
      ts[(long)b * H + ch * 128 + t] = s * (1.f / 32.f);
    }
#pragma unroll 8
    for (int c = 0; c < 32; ++c) {
      f32x4 kv = *(const f32x4*)&tile[p][l][c * 4];
      f32x4 qv = *(const f32x4*)(qrow + ch * 128 + c * 4);
      sc += kv[0] * qv[0] + kv[1] * qv[1] + kv[2] * qv[2] + kv[3] * qv[3];
    }
    p ^= 1;
  }

  float mx = sc;
#pragma unroll
  for (int m = 16; m >= 1; m >>= 1) mx = fmaxf(mx, __shfl_xor(mx, m, 32));
  float pr = __expf(sc - mx);
  float sum = pr;
#pragma unroll
  for (int m = 16; m >= 1; m >>= 1) sum += __shfl_xor(sum, m, 32);
  pr /= sum;
  p_s[head][l] = pr;  // made visible by the barrier inside the V loop

  for (int ch = 0; ch < 8; ++ch) {
    __syncthreads();
#pragma unroll
    for (int it = 0; it < 4; ++it) *(f32x4*)&tile[p][rr[it]][cc4[it] * 4] = R[it];
    if (ch < 7) {
#pragma unroll
      for (int it = 0; it < 4; ++it)
        R[it] = *(const f32x4*)(baseV[it] + (ch + 1) * 128 + cc4[it] * 4);
    }
    __syncthreads();
    float a0 = 0.f, a1 = 0.f, a2 = 0.f, a3 = 0.f;
#pragma unroll
    for (int lr = 0; lr < 32; ++lr) {
      float pw = p_s[head][lr];
      a0 += pw * tile[p][lr][l];
      a1 += pw * tile[p][lr][l + 32];
      a2 += pw * tile[p][lr][l + 64];
      a3 += pw * tile[p][lr][l + 96];
    }
    long o = (long)head * 1024 + ch * 128 + l;
    mix[o] = a0; mix[o + 32] = a1; mix[o + 64] = a2; mix[o + 96] = a3;
    p ^= 1;
  }
}

extern "C" void kernel_launch(void* const* d_in, const int* in_sizes, int n_in,
                              void* d_out, int out_size, void* d_ws, size_t ws_size,
                              hipStream_t stream) {
  const float* x    = (const float*)d_in[0];
  const float* h    = (const float*)d_in[1];
  const float* c    = (const float*)d_in[2];
  const float* memK = (const float*)d_in[3];
  const float* memV = (const float*)d_in[4];
  const float* extK = (const float*)d_in[5];
  const float* extV = (const float*)d_in[6];
  const float* W_ih = (const float*)d_in[7];
  const float* W_hh = (const float*)d_in[8];
  const float* b_ih = (const float*)d_in[9];
  const float* b_hh = (const float*)d_in[10];
  const float* sWq = (const float*)d_in[11];
  const float* sbq = (const float*)d_in[12];
  const float* sWk = (const float*)d_in[13];
  const float* sWv = (const float*)d_in[15];
  const float* sbv = (const float*)d_in[16];
  const float* sWo = (const float*)d_in[17];
  const float* sbo = (const float*)d_in[18];
  const float* cWq = (const float*)d_in[19];
  const float* cbq = (const float*)d_in[20];
  const float* cWk = (const float*)d_in[21];
  const float* cWv = (const float*)d_in[23];
  const float* cbv = (const float*)d_in[24];
  const float* cWo = (const float*)d_in[25];
  const float* cbo = (const float*)d_in[26];
  const float* Wres = (const float*)d_in[27];
  const float* bres = (const float*)d_in[28];
  const float* Wrout = (const float*)d_in[29];
  const float* brout = (const float*)d_in[30];
  const float* Wcomp = (const float*)d_in[31];
  const float* bcomp = (const float*)d_in[32];
  const float* Wexp = (const float*)d_in[33];
  const float* bexp = (const float*)d_in[34];
  const float* Wgate = (const float*)d_in[35];
  const float* bgate = (const float*)d_in[36];
  (void)in_sizes; (void)n_in; (void)out_size; (void)ws_size;

  float* out = (float*)d_out;
  float* w = (float*)d_ws;
  const long M1 = 1024 * 1024;
  float* gates   = w;            // 8M
  float* hl      = w + 8 * M1;   // 2M
  float* qsS     = w + 10 * M1;  // 2M
  float* qsE     = w + 12 * M1;  // 2M
  float* wkTs    = w + 14 * M1;  // 1M
  float* wkTc    = w + 15 * M1;  // 1M
  float* qtS     = w + 16 * M1;  // 16M
  float* qtE     = w + 32 * M1;  // 16M
  float* mixS    = w + 48 * M1;  // 16M
  float* mixE    = w + 64 * M1;  // 16M
  float* ts      = w + 80 * M1;  // 2M
  float* attnS   = w + 82 * M1;  // 2M
  float* attnE   = w + 84 * M1;  // 2M
  float* selfO   = w + 86 * M1;  // 2M
  float* extO    = w + 88 * M1;  // 2M
  float* rw      = w + 90 * M1;  // 4K
  float* rattn   = w + 91 * M1;  // 2M
  float* routed  = w + 93 * M1;  // 2M
  float* comp    = w + 95 * M1;  // 0.5M
  float* expd    = w + 96 * M1;  // 2M

  float* hFinal_out = out;
  float* hl_out     = out + 2 * M1;
  float* cn_out     = out + 4 * M1;

  const float scaleq = 0.08838834764831845f;  // 1/sqrt(128)
  const int ZBIG = 1 << 30;
  dim3 blk(256);
  const float* nf = nullptr;

  transpose_k<<<dim3(16, 16), blk, 0, stream>>>(sWk, wkTs, 1024);
  transpose_k<<<dim3(16, 16), blk, 0, stream>>>(cWk, wkTc, 1024);

  // gates = x@W_ih^T + h@W_hh^T + b_ih + b_hh  (K-concat both sides)
  gemm_k<1, 1, 0><<<dim3(32, 16, 1), blk, 0, stream>>>(
      x, nf, 1024, 0, h, 1024, 1024,
      W_ih, nf, 1024, 0, W_hh, 1024,
      b_ih, nf, 0, b_hh,
      gates, nullptr, 4096, 0,
      2048, ZBIG, 1.f, nf, nf, nf, nf);

  lstm_k<<<2048, blk, 0, stream>>>(gates, c, cn_out, hl, hl_out);

  // qs (self z=0, ext z=1), scaled
  gemm_k<0, 0, 0><<<dim3(8, 16, 2), blk, 0, stream>>>(
      hl, hl, 1024, 0, nf, 0, 0,
      sWq, cWq, 1024, 0, nf, 0,
      sbq, cbq, 0, nf,
      qsS, qsE, 1024, 0,
      1024, 1, scaleq, nf, nf, nf, nf);

  // qt[b,h,k] = sum_d qs[b,h*128+d]*WkT[k,h*128+d]; z: 0-7 self heads, 8-15 ext
  gemm_k<0, 0, 0><<<dim3(8, 16, 16), blk, 0, stream>>>(
      qsS, qsE, 1024, 128, nf, 0, 0,
      wkTs, wkTc, 1024, 128, nf, 0,
      nf, nf, 0, nf,
      qtS, qtE, 8192, 1024,
      128, 8, 1.f, nf, nf, nf, nf);

  // fused attention, self+ext
  attn2_k<<<dim3(2048, 2), blk, 0, stream>>>(memK, memV, extK, extV, hl,
                                             qtS, qtE, mixS, mixE, ts);

  // attn[b, h*128+d] = mix[b,h,:]@Wv_h^T + bv ; z: 0-7 self, 8-15 ext
  gemm_k<0, 0, 0><<<dim3(1, 16, 16), blk, 0, stream>>>(
      mixS, mixE, 8192, 1024, nf, 0, 0,
      sWv, cWv, 1024, 131072, nf, 0,
      sbv, cbv, 128, nf,
      attnS, attnE, 1024, 128,
      1024, 8, 1.f, nf, nf, nf, nf);

  // output projections (z=0 self, z=1 ext)
  gemm_k<0, 0, 0><<<dim3(8, 16, 2), blk, 0, stream>>>(
      attnS, attnE, 1024, 0, nf, 0, 0,
      sWo, cWo, 1024, 0, nf, 0,
      sbo, cbo, 0, nf,
      selfO, extO, 1024, 0,
      1024, 1, 1.f, nf, nf, nf, nf);

  router_k<<<2048, dim3(64), 0, stream>>>(hl, Wrout, brout, rw);
  combine_k<<<2048, blk, 0, stream>>>(selfO, extO, rw, rattn);

  // routed = h_lstm + rattn + rattn@Wres^T + bres
  gemm_k<0, 0, 1><<<dim3(8, 16, 1), blk, 0, stream>>>(
      rattn, nf, 1024, 0, nf, 0, 0,
      Wres, nf, 1024, 0, nf, 0,
      bres, nf, 0, nf,
      routed, nullptr, 1024, 0,
      1024, ZBIG, 1.f, hl, rattn, nf, nf);

  // compressed / expanded
  gemm_k<0, 0, 0><<<dim3(2, 16, 1), blk, 0, stream>>>(
      ts, nf, 1024, 0, nf, 0, 0,
      Wcomp, nf, 1024, 0, nf, 0,
      bcomp, nf, 0, nf,
      comp, nullptr, 256, 0,
      1024, ZBIG, 1.f, nf, nf, nf, nf);
  gemm_k<0, 0, 0><<<dim3(8, 16, 1), blk, 0, stream>>>(
      comp, nf, 256, 0, nf, 0, 0,
      Wexp, nf, 256, 0, nf, 0,
      bexp, nf, 0, nf,
      expd, nullptr, 1024, 0,
      256, ZBIG, 1.f, nf, nf, nf, nf);

  // gate GEMM (A = [x | routed] K-concat) + fused final epilogue
  gemm_k<1, 0, 2><<<dim3(8, 16, 1), blk, 0, stream>>>(
      x, nf, 1024, 0, routed, 1024, 1024,
      Wgate, nf, 2048, 0, nf, 0,
      bgate, nf, 0, nf,
      hFinal_out, nullptr, 1024, 0,
      2048, ZBIG, 1.f, comp, expd, hl, routed);
}